// Round 8
// baseline (1265.668 us; speedup 1.0000x reference)
//
#include <hip/hip_runtime.h>

// LSTMStateEstimation: 2-layer LSTM (B=64,T=256,IN=128,H=512) + FC(512->64).
//
// r17 = r16 (877us) + VALUE-VALIDATED handoff (sentinel protocol).
// The flag wait existed only to validate staged data. r17 validates the
// DATA: h values are bf16 of sigmoid/tanh products (never NaN); sentinel =
// 0xFFFF (bf16 NaN). Consumers spin-load their granules until both 8B
// halves are non-sentinel. This removes the producer drain AND the
// flag-detect hop from the data path: producer ISSUES stores first after
// the tail barrier; consumers' spinning loads see the data as it lands.
//   - rings deepen to 16 slots; slot(tau) = (tau+1)&15; slot 0 = zeros
//     (= valid h[-1]); slots 1..15 init 0xFF sentinel (host memset).
//   - stale-reuse guards: (1) L1 wave0 lazy CLEAR CURSORS re-sentinel
//     consumed slots (gated on non-blocking flag minima, ~13 steps slack);
//     (2) loaders fold a flag1 >= t-8 check into the data spin (implied
//     true by the prior step's gates -> zero latency); (3) L0's blocking
//     pre-store gate flag1 >= t-7 (the lead-8 throttle; also proves the
//     clear of the slot it overwrites landed).
//   - flags/drains retained PRODUCER-side only (WAR bookkeeping + FC),
//     ordered stores -> snapshot -> clears -> vmcnt(0) -> flag.
// Everything else r16: MALL primitives (sc0sc1 loads / agent-atomic
// stores), loader-storer wave split, in-register gate tail, h_lds8 pack +
// wave0 coalesced 8B stores, L1 h0 LDS-prefetch dbuf, hot polls, bounded.

#define NB    64
#define SEQL  256
#define INF   128
#define HID   512
#define OUTN  64
#define NWG   256
#define NT    256
#define NCNT  32
#define CADD  (NWG / NCNT)
#define PBOUND 8192

typedef __attribute__((ext_vector_type(8))) short  short8;
typedef __attribute__((ext_vector_type(4))) float  floatx4;
typedef unsigned short u16;
typedef unsigned long long u64;

#define TIE4(N, x0,x1,x2,x3)                                                \
  asm volatile("s_waitcnt vmcnt(" N ")" : "+v"(x0), "+v"(x1), "+v"(x2), "+v"(x3))
#define TIE2(N, x0,x1)                                                      \
  asm volatile("s_waitcnt vmcnt(" N ")" : "+v"(x0), "+v"(x1))

#define MFMA(ACC, A, B) \
  ACC = __builtin_amdgcn_mfma_f32_16x16x32_bf16((A), (B), ACC, 0, 0, 0)

__device__ __forceinline__ u16 f2bf(float f) {
  union { float f; unsigned u; } v; v.f = f;
  return (u16)((v.u + 0x7FFFu + ((v.u >> 16) & 1u)) >> 16);  // RNE
}
__device__ __forceinline__ float bf2f(u16 s) {
  union { unsigned u; float f; } v; v.u = ((unsigned)s) << 16;
  return v.f;
}
__device__ __forceinline__ float sigf(float v) {
  return __builtin_amdgcn_rcpf(1.f + __expf(-v));
}
__device__ __forceinline__ float tanh_fast(float v) {
  float cv = fminf(fmaxf(v, -15.f), 15.f);
  float e = __expf(2.f * cv);
  return (e - 1.f) * __builtin_amdgcn_rcpf(e + 1.f);
}

// ---- proven exchange primitives (r4/r5-validated on MI355X) ----
__device__ __forceinline__ short8 ldh(const u16* p) {
  short8 d;
  asm volatile("global_load_dwordx4 %0, %1, off sc0 sc1" : "=v"(d) : "v"(p));
  return d;
}
__device__ __forceinline__ void st8c(u16* p, u64 v) {
  __hip_atomic_store((u64*)p, v, __ATOMIC_RELAXED, __HIP_MEMORY_SCOPE_AGENT);
}
__device__ __forceinline__ unsigned ldf(const unsigned* p) {
  return __hip_atomic_load(p, __ATOMIC_RELAXED, __HIP_MEMORY_SCOPE_AGENT);
}

// granule validity: both 8B halves non-sentinel (producer stores are 8B
// atomics; 0xFFFF = bf16 NaN, unreachable by real h values)
__device__ __forceinline__ bool valid8(short8 v) {
  return ((u16)v[0] != 0xFFFFu) & ((u16)v[4] != 0xFFFFu);
}

// staging-granule LDS byte offset (XOR-swizzle byte ^= (b&7)<<4)
__device__ __forceinline__ int swz(int gi) {
  return (gi * 16) ^ (((gi >> 6) & 7) << 4);
}

// blocking flag wait: lanes 0-15 poll f[0..15] >= thr (thr<=0 vacuous);
// hot spin, bounded, trailing fence.
__device__ __forceinline__ void wait_ge(const unsigned* f, int thr) {
  if (thr <= 0) return;
  const int lane = threadIdx.x & 63;
  const unsigned* p = (lane < 16) ? f + lane : nullptr;
  for (int i = 0; i < PBOUND; ++i) {
    int v = 0x7fffffff;
    if (p) v = (int)ldf(p);
    if (__all(v >= thr)) break;
    if (i > 2048) __builtin_amdgcn_s_sleep(2);
  }
  __builtin_amdgcn_sched_barrier(0);
  asm volatile("" ::: "memory");
}

// One-time MALL grid barrier (r5-proven shape), bounded poll.
__device__ __forceinline__ void grid_bar_once(unsigned* leaf, int w) {
  asm volatile("s_waitcnt vmcnt(0)" ::: "memory");
  __syncthreads();
  if (threadIdx.x == 0)
    __hip_atomic_fetch_add(&leaf[(w & (NCNT - 1)) * 32], 1u, __ATOMIC_RELAXED,
                           __HIP_MEMORY_SCOPE_AGENT);
  if (threadIdx.x < 64) {
    const int lane = threadIdx.x & 63;
    for (int i = 0; i < (1 << 16); ++i) {
      unsigned v = CADD;
      if (lane < NCNT) v = ldf(&leaf[lane * 32]);
      if (__all(v >= CADD)) break;
      __builtin_amdgcn_s_sleep(1);
    }
  }
  __syncthreads();
}

// 4x4 transpose across a lane quartet (lanes base..base+3, j = lane&3).
__device__ __forceinline__ floatx4 xpose4(floatx4 v, int jb0, int jb1) {
  floatx4 t;
#pragma unroll
  for (int r = 0; r < 4; ++r) t[r] = __shfl_xor(v[r], 1);
  floatx4 u;
  u[0] = jb0 ? t[1] : v[0];
  u[1] = jb0 ? v[1] : t[0];
  u[2] = jb0 ? t[3] : v[2];
  u[3] = jb0 ? v[3] : t[2];
  floatx4 s;
#pragma unroll
  for (int r = 0; r < 4; ++r) s[r] = __shfl_xor(u[r], 2);
  floatx4 w_;
  w_[0] = jb1 ? s[2] : u[0];
  w_[1] = jb1 ? s[3] : u[1];
  w_[2] = jb1 ? u[2] : s[0];
  w_[3] = jb1 ? u[3] : s[1];
  return w_;
}

// B-fragments (r9-shape, unchanged).
template <int KS, int KIN>
__device__ __forceinline__ void load_B(short8 (&Bf)[2][32],
                                       const float* __restrict__ Wih,
                                       const float* __restrict__ Whh,
                                       int li, int wv, int mrow, int quad) {
#pragma unroll
  for (int t2 = 0; t2 < 2; ++t2) {
    const int rowid = wv * 32 + t2 * 16 + mrow;
    const int r = (rowid & 3) * HID + 32 * li + (rowid >> 2);
    const float* wr = Wih + (size_t)r * KIN;
    const float* hr = Whh + (size_t)r * HID - KIN;   // hr[k]=Whh[r][k-KIN]
#pragma unroll
    for (int ks = 0; ks < KS; ++ks) {
      short8 v;
#pragma unroll
      for (int j = 0; j < 8; ++j) {
        const int k = 32 * ks + quad * 8 + j;
        v[j] = (short)f2bf(k < KIN ? wr[k] : hr[k]);
      }
      Bf[t2][ks] = v;
    }
  }
}

__global__ __launch_bounds__(NT, 1) void lstm_groups(
    const float* __restrict__ x,
    const float* __restrict__ Wih0, const float* __restrict__ Whh0,
    const float* __restrict__ bih0, const float* __restrict__ bhh0,
    const float* __restrict__ Wih1, const float* __restrict__ Whh1,
    const float* __restrict__ bih1, const float* __restrict__ bhh1,
    const float* __restrict__ Wfc,  const float* __restrict__ bfc,
    float* __restrict__ out,
    unsigned* __restrict__ leaf,
    unsigned* __restrict__ flag0, unsigned* __restrict__ flag1,
    u16* __restrict__ h0r, u16* __restrict__ h1r, u16* __restrict__ xg)
{
  const int w = blockIdx.x, tid = threadIdx.x;
  const int lane = tid & 63, wv = tid >> 6;
  const int quad = lane >> 4, mrow = lane & 15;
  const int g = w & 7, m = w >> 3;          // group, member (0..31)
  const bool isL1 = (m >= 16);
  const int  li   = isL1 ? m - 16 : m;      // layer-local WG index (0..15)

  __shared__ u64   h_lds8[8][8];
  __shared__ float red[16][17];
  // staging: [b(8)][k(512)] bf16 = 8KB per buffer, XOR-swizzle byte^=(b&7)<<4.
  // hA2: L0 h-stage (buf0 only) / L1 h0-prefetch dbuf.  hB: L1 h1-stage.
  __shared__ short8 hA2[2][512];
  __shared__ short8 hB[512];
  char* hAc = (char*)hA2;
  char* hBc = (char*)hB;

  // ---- xg fill: xg[g][t][b][k] bf16, 8 (g,t)-slices per WG, MALL stores ----
#pragma unroll
  for (int i = 0; i < 8; ++i) {
    const int s = w * 8 + i, gs = s >> 8, ts = s & 255;
    u16* dst = xg + (size_t)(gs * 256 + ts) * 1024;
    const int b = tid >> 5, k0 = (tid & 31) * 4;
    const float* src = x + ((size_t)(8 * gs + b) * SEQL + ts) * INF + k0;
    union { u16 h[4]; u64 u; } pk;
#pragma unroll
    for (int j = 0; j < 4; ++j) pk.h[j] = f2bf(src[j]);
    st8c(dst + b * 128 + k0, pk.u);
  }

  // ---- weights -> VGPR B-fragments; bias -> regs (folded into acc init) --
  short8 Bf[2][32];
  if (isL1) load_B<32, HID>(Bf, Wih1, Whh1, li, wv, mrow, quad);
  else      load_B<20, INF>(Bf, Wih0, Whh0, li, wv, mrow, quad);
  float bsA, bsB;
  {
    const int r0 = wv * 32 + mrow, r1 = r0 + 16;
    const int ra = (r0 & 3) * HID + 32 * li + (r0 >> 2);
    const int rb = (r1 & 3) * HID + 32 * li + (r1 >> 2);
    bsA = isL1 ? (bih1[ra] + bhh1[ra]) : (bih0[ra] + bhh0[ra]);
    bsB = isL1 ? (bih1[rb] + bhh1[rb]) : (bih0[rb] + bhh0[rb]);
  }

  grid_bar_once(leaf, w);   // xg visible everywhere; flags zero; rings init'd

  // flags: flag[g*64 + li] = t+1 (producer completed step t)
  unsigned* flag0g = flag0 + g * 64;
  unsigned* flag1g = flag1 + g * 64;
  // rings: 16 slots x 8KB; slot(tau) = (tau+1)&15; slot0 = zeros = h[-1]
  u16* h0g = h0r + (size_t)g * 65536;
  u16* h1g = h1r + (size_t)g * 65536;
  const u16* xgg = xg + (size_t)g * 256 * 1024;

  const int q4 = quad;
  const int m4 = mrow >> 2, jg = mrow & 3;
  const int jb0 = jg & 1, jb1 = (jg >> 1) & 1;
  float cstA = 0.f, cstB = 0.f;
  const int ab = mrow & 7;
  const int koff = quad * 8;

  const bool ldr = (wv != 0);        // loader waves 1-3; wave 0 = storer
  const int base = tid - 64;         // loader granule base (0..191)
  int c0 = -1, c1 = -1;              // L1 wave0 clear cursors (next s to clear)

  // L1 pre-stage: sentinel-poll h0[0] (slot 1) -> hA2 buf0. All 256 threads.
  if (isL1) {
    const u16* sp = h0g + 1 * 4096;
    short8 s0 = {}, s1 = {};
    bool done = false;
    for (int it = 0; it < PBOUND && !done; ++it) {
      s0 = ldh(sp + tid * 8);
      s1 = ldh(sp + (tid + 256) * 8);
      TIE2("0", s0, s1);
      done = __all(valid8(s0) & valid8(s1));
      if (it > 2048) __builtin_amdgcn_s_sleep(2);
    }
    __builtin_amdgcn_sched_barrier(0);
    *(short8*)(hAc + swz(tid)) = s0;
    *(short8*)(hAc + swz(tid + 256)) = s1;
    __syncthreads();
  }

  for (int t = 0; t < SEQL; ++t) {
    floatx4 a00 = {bsA, bsA, bsA, bsA}, a01 = {0,0,0,0};
    floatx4 a10 = {bsB, bsB, bsB, bsB}, a11 = {0,0,0,0};
    const int pb = (t & 1) * 8192;        // L1 prefetch: current buffer
    const int nb_ = ((t + 1) & 1) * 8192; // L1 prefetch: next buffer
    const int thr = t - 8;                // loader stale-guard (slack, free)

    if (!isL1) {
      // x-part: cached xg loads + 8 MFMAs (all waves, before any wait)
      const u16* xa = xgg + (size_t)t * 1024 + ab * 128 + koff;
      short8 x0 = *(const short8*)(xa +  0);
      short8 x1 = *(const short8*)(xa + 32);
      short8 x2 = *(const short8*)(xa + 64);
      short8 x3 = *(const short8*)(xa + 96);
      MFMA(a00,x0,Bf[0][0]);  MFMA(a10,x0,Bf[1][0]);
      MFMA(a01,x1,Bf[0][1]);  MFMA(a11,x1,Bf[1][1]);
      MFMA(a00,x2,Bf[0][2]);  MFMA(a10,x2,Bf[1][2]);
      MFMA(a01,x3,Bf[0][3]);  MFMA(a11,x3,Bf[1][3]);

      if (ldr) {
        // sentinel-spin h0[t-1] (slot t&15) + concurrent flag1>=t-8 guard
        const u16* src = h0g + (t & 15) * 4096;
        const bool g2 = (base < 128);
        short8 s0 = {}, s1 = {}, s2 = {};
        bool done = false;
        for (int it = 0; it < PBOUND && !done; ++it) {
          s0 = ldh(src + base * 8);
          s1 = ldh(src + (base + 192) * 8);
          if (g2) s2 = ldh(src + (base + 384) * 8);
          int fl = 0x7fffffff;
          if (lane < 16 && thr > 0) fl = (int)ldf(flag1g + lane);
          asm volatile("s_waitcnt vmcnt(0)" : "+v"(s0), "+v"(s1), "+v"(s2));
          bool v = valid8(s0) & valid8(s1) & (!g2 | valid8(s2)) & (fl >= thr);
          done = __all(v);
          if (it > 2048) __builtin_amdgcn_s_sleep(2);
        }
        __builtin_amdgcn_sched_barrier(0);
        *(short8*)(hAc + swz(base)) = s0;
        *(short8*)(hAc + swz(base + 192)) = s1;
        if (g2) *(short8*)(hAc + swz(base + 384)) = s2;
      }
      __syncthreads();   // stage-publish barrier

#pragma unroll
      for (int n = 0; n < 16; ++n) {
        const short8 fv = *(const short8*)(
            hAc + ((ab * 1024 + n * 64 + quad * 16) ^ (ab << 4)));
        if ((n & 1) == 0) { MFMA(a00, fv, Bf[0][4 + n]); MFMA(a10, fv, Bf[1][4 + n]); }
        else              { MFMA(a01, fv, Bf[0][4 + n]); MFMA(a11, fv, Bf[1][4 + n]); }
      }
    } else {
      const bool pf = (t < 255);           // prefetch h0[t+1] exists
      if (ldr) {
        const u16* srcB = h1g + (t & 15) * 4096;        // h1[t-1]
        const u16* srcP = h0g + ((t + 2) & 15) * 4096;  // h0[t+1]
        const bool g2 = (base < 128);
        short8 b0 = {}, b1 = {}, b2 = {}, p0 = {}, p1 = {}, p2 = {};
        // round 1: issue loads, run the 16 h0-part MFMAs in the shadow
        b0 = ldh(srcB + base * 8);
        b1 = ldh(srcB + (base + 192) * 8);
        if (g2) b2 = ldh(srcB + (base + 384) * 8);
        if (pf) {
          p0 = ldh(srcP + base * 8);
          p1 = ldh(srcP + (base + 192) * 8);
          if (g2) p2 = ldh(srcP + (base + 384) * 8);
        }
        __builtin_amdgcn_sched_barrier(0);
#pragma unroll
        for (int n = 0; n < 16; ++n) {
          const short8 fv = *(const short8*)(
              hAc + pb + ((ab * 1024 + n * 64 + quad * 16) ^ (ab << 4)));
          if ((n & 1) == 0) { MFMA(a00, fv, Bf[0][n]); MFMA(a10, fv, Bf[1][n]); }
          else              { MFMA(a01, fv, Bf[0][n]); MFMA(a11, fv, Bf[1][n]); }
        }
        bool done = false;
        for (int it = 0; it < PBOUND && !done; ++it) {
          if (it) {
            b0 = ldh(srcB + base * 8);
            b1 = ldh(srcB + (base + 192) * 8);
            if (g2) b2 = ldh(srcB + (base + 384) * 8);
            if (pf) {
              p0 = ldh(srcP + base * 8);
              p1 = ldh(srcP + (base + 192) * 8);
              if (g2) p2 = ldh(srcP + (base + 384) * 8);
            }
          }
          int fl = 0x7fffffff;
          if (lane < 16 && thr > 0) fl = (int)ldf(flag1g + lane);
          asm volatile("s_waitcnt vmcnt(0)"
                       : "+v"(b0), "+v"(b1), "+v"(b2),
                         "+v"(p0), "+v"(p1), "+v"(p2));
          bool v = valid8(b0) & valid8(b1) & (!g2 | valid8(b2)) & (fl >= thr);
          if (pf) v = v & valid8(p0) & valid8(p1) & (!g2 | valid8(p2));
          done = __all(v);
          if (it > 2048) __builtin_amdgcn_s_sleep(2);
        }
        __builtin_amdgcn_sched_barrier(0);
        *(short8*)(hBc + swz(base)) = b0;
        *(short8*)(hBc + swz(base + 192)) = b1;
        if (g2) *(short8*)(hBc + swz(base + 384)) = b2;
        if (pf) {
          *(short8*)(hAc + nb_ + swz(base)) = p0;
          *(short8*)(hAc + nb_ + swz(base + 192)) = p1;
          if (g2) *(short8*)(hAc + nb_ + swz(base + 384)) = p2;
        }
      } else {
        // wave0: its 16 h0-part MFMAs from prefetched LDS
#pragma unroll
        for (int n = 0; n < 16; ++n) {
          const short8 fv = *(const short8*)(
              hAc + pb + ((ab * 1024 + n * 64 + quad * 16) ^ (ab << 4)));
          if ((n & 1) == 0) { MFMA(a00, fv, Bf[0][n]); MFMA(a10, fv, Bf[1][n]); }
          else              { MFMA(a01, fv, Bf[0][n]); MFMA(a11, fv, Bf[1][n]); }
        }
      }
      __syncthreads();   // stage-publish barrier (hB + hA[nb_])

#pragma unroll
      for (int n = 0; n < 16; ++n) {
        const short8 fv = *(const short8*)(
            hBc + ((ab * 1024 + n * 64 + quad * 16) ^ (ab << 4)));
        if ((n & 1) == 0) { MFMA(a00, fv, Bf[0][16 + n]); MFMA(a10, fv, Bf[1][16 + n]); }
        else              { MFMA(a01, fv, Bf[0][16 + n]); MFMA(a11, fv, Bf[1][16 + n]); }
      }
    }

    // ---- in-register tail: transpose -> gates -> h_lds8 ----
    const floatx4 vA = a00 + a01, vB = a10 + a11;
    if (lane < 32) {
      const floatx4 gA = xpose4(vA, jb0, jb1);
      const floatx4 gB = xpose4(vB, jb0, jb1);
      const float cA = sigf(gA[1]) * cstA + sigf(gA[0]) * tanh_fast(gA[2]);
      const float cB = sigf(gB[1]) * cstB + sigf(gB[0]) * tanh_fast(gB[2]);
      cstA = cA; cstB = cB;
      u16* hl = (u16*)&h_lds8[q4 * 4 + jg][0];
      hl[wv * 8 + m4]     = f2bf(sigf(gA[3]) * tanh_fast(cA));
      hl[wv * 8 + m4 + 4] = f2bf(sigf(gB[3]) * tanh_fast(cB));
    }
    __syncthreads();   // tail-publish barrier

    if (wv == 0) {
      u16* ring = isL1 ? h1g : h0g;
      if (!isL1) {
        // lead/WAR gate: L1 completed t-8 => clears of slot (t+1)&15 landed
        wait_ge(flag1g, t - 7);
      }
      // DATA STORES FIRST (consumers see them as they land; no drain gate)
      {
        const int b = tid >> 3, u8 = tid & 7;
        const u64 v = h_lds8[b][u8];
        st8c(ring + ((t + 1) & 15) * 4096 + b * 512 + li * 32 + u8 * 4, v);
      }
      if (isL1) {
        // flag snapshot (one round) -> advance clear cursors
        unsigned vmin = 0x7fffffffu;
        if (lane < 16)       vmin = ldf(flag0g + lane);
        else if (lane < 32)  vmin = ldf(flag1g + lane - 16);
#pragma unroll
        for (int o = 1; o < 16; o <<= 1) {
          unsigned ov = (unsigned)__shfl_xor((int)vmin, o);
          vmin = vmin < ov ? vmin : ov;
        }
        const int m0 = __shfl((int)vmin, 0);
        const int m1 = __shfl((int)vmin, 16);
        int tgt0 = m0 - 2; if (m1 - 1 < tgt0) tgt0 = m1 - 1;
        if (t - 1 < tgt0) tgt0 = t - 1;
        while (c0 <= tgt0) {   // clear h0[c0] (slot (c0+1)&15), li-range
          st8c(h0g + ((c0 + 1) & 15) * 4096 + li * 256 + lane * 4,
               0xFFFFFFFFFFFFFFFFull);
          ++c0;
        }
        int tgt1 = m1 - 2; if (t - 1 < tgt1) tgt1 = t - 1;
        while (c1 <= tgt1) {   // clear h1[c1], li-range
          st8c(h1g + ((c1 + 1) & 15) * 4096 + li * 256 + lane * 4,
               0xFFFFFFFFFFFFFFFFull);
          ++c1;
        }
      }
      // drain (stores + clears) then publish flag (WAR bookkeeping only)
      asm volatile("s_waitcnt vmcnt(0)" ::: "memory");
      if (tid == 0)
        __hip_atomic_store((isL1 ? flag1g : flag0g) + li, (unsigned)(t + 1),
                           __ATOMIC_RELAXED, __HIP_MEMORY_SCOPE_AGENT);
    }
  }

  // ---- FC head: out[b][o] = h1_255[b] . Wfc[o] + bfc[o] ----
  // h1[255] lives in slot (255+1)&15 = 0. Flag wait = completion + drain.
  {
    const int lane_ = tid & 63;
    const unsigned* p = (lane_ < 16) ? flag1g + lane_ : nullptr;
    for (int i = 0; i < PBOUND; ++i) {
      int v = 0x7fffffff;
      if (p) v = (int)ldf(p);
      if (__all(v >= 256)) break;
      if (i > 2048) __builtin_amdgcn_s_sleep(2);
    }
    __builtin_amdgcn_sched_barrier(0);
    asm volatile("" ::: "memory");
  }
  {
    const int bloc = m >> 2, oq = m & 3;    // 32 members = 8 b x 4 o-blocks
    const int ol = tid >> 4, ksub = tid & 15;
    const u16* hp = h1g + 0 * 4096 + bloc * 512 + ksub * 32;
    short8 v0 = ldh(hp),      v1 = ldh(hp + 8);
    short8 v2 = ldh(hp + 16), v3 = ldh(hp + 24);
    TIE4("0", v0, v1, v2, v3);
    const float* wr = Wfc + (size_t)(oq * 16 + ol) * HID + ksub * 32;
    float s = 0.f;
#pragma unroll
    for (int j = 0; j < 8; ++j) {
      s += bf2f((u16)v0[j]) * wr[j];
      s += bf2f((u16)v1[j]) * wr[8 + j];
      s += bf2f((u16)v2[j]) * wr[16 + j];
      s += bf2f((u16)v3[j]) * wr[24 + j];
    }
    red[ol][ksub] = s;
    __syncthreads();
    if (tid < 16) {
      float sum = 0.f;
#pragma unroll
      for (int j = 0; j < 16; ++j) sum += red[tid][j];
      out[(size_t)(8 * g + bloc) * OUTN + oq * 16 + tid] = sum + bfc[oq * 16 + tid];
    }
  }
}

// Workspace layout (bytes):
//   [256, 4352)          one-time barrier leaves (32 x 128B)
//   [8192, 10240)        flag0[8][64] u32 (per-WG monotonic, 16 used)
//   [16384, 18432)       flag1[8][64] u32
//   [32768, 1081344)     h0 rings: 8 groups x 16 slots x 8 b x 512 k bf16
//   [1081344, 2129920)   h1 rings (same shape)
//   [2129920, 6324224)   xg: 8 groups x 256 t x 8 b x 128 k bf16
// init: [0,32768)=0; rings=0xFF (sentinel); slot0 of each group/ring = 0
// (valid h[-1] zeros); xg fully written by kernel.

extern "C" void kernel_launch(void* const* d_in, const int* in_sizes, int n_in,
                              void* d_out, int out_size, void* d_ws, size_t ws_size,
                              hipStream_t stream) {
  (void)in_sizes; (void)n_in; (void)out_size; (void)ws_size;

  char* ws = (char*)d_ws;
  unsigned* leaf  = (unsigned*)(ws + 256);
  unsigned* flag0 = (unsigned*)(ws + 8192);
  unsigned* flag1 = (unsigned*)(ws + 16384);
  u16* h0r = (u16*)(ws + 32768);
  u16* h1r = (u16*)(ws + 1081344);
  u16* xg  = (u16*)(ws + 2129920);

  hipMemsetAsync(d_ws, 0, 32768, stream);                 // leaf + flags
  hipMemsetAsync(ws + 32768, 0xFF, 2097152, stream);      // rings -> sentinel
  for (int gg = 0; gg < 8; ++gg) {                        // slot0 -> zeros
    hipMemsetAsync(ws + 32768   + gg * 131072, 0, 8192, stream);
    hipMemsetAsync(ws + 1081344 + gg * 131072, 0, 8192, stream);
  }

  const float* x    = (const float*)d_in[0];
  const float* Wih0 = (const float*)d_in[1];
  const float* Whh0 = (const float*)d_in[2];
  const float* bih0 = (const float*)d_in[3];
  const float* bhh0 = (const float*)d_in[4];
  const float* Wih1 = (const float*)d_in[5];
  const float* Whh1 = (const float*)d_in[6];
  const float* bih1 = (const float*)d_in[7];
  const float* bhh1 = (const float*)d_in[8];
  const float* Wfc  = (const float*)d_in[9];
  const float* bfc  = (const float*)d_in[10];
  float* out = (float*)d_out;

  void* args[] = {
    (void*)&x,
    (void*)&Wih0, (void*)&Whh0, (void*)&bih0, (void*)&bhh0,
    (void*)&Wih1, (void*)&Whh1, (void*)&bih1, (void*)&bhh1,
    (void*)&Wfc,  (void*)&bfc,
    (void*)&out,
    (void*)&leaf, (void*)&flag0, (void*)&flag1,
    (void*)&h0r, (void*)&h1r, (void*)&xg
  };
  hipError_t err = hipLaunchCooperativeKernel((const void*)lstm_groups,
                                              dim3(NWG), dim3(NT), args, 0, stream);
  if (err != hipSuccess) {
    // 256 blocks @ 1 block/CU on 256 CUs are co-resident structurally.
    hipLaunchKernelGGL(lstm_groups, dim3(NWG), dim3(NT), 0, stream,
                       x, Wih0, Whh0, bih0, bhh0, Wih1, Whh1, bih1, bhh1,
                       Wfc, bfc, out, leaf, flag0, flag1, h0r, h1r, xg);
  }
}

// Round 10
// 1079.063 us; speedup vs baseline: 1.1729x; 1.1729x over previous
//
#include <hip/hip_runtime.h>

// LSTMStateEstimation: 2-layer LSTM (B=64,T=256,IN=128,H=512) + FC(512->64).
//
// r19 = r18 resubmitted verbatim (round 9 failed at the infra level:
// "MI355X container failed twice", no test output). r18's protocol was
// re-audited this round: bounded polls (worst case = visible wrong answer,
// never a dead GPU), slot-0 zeros hazard handled by cursors starting at -1,
// WAR chain (clear drained into flag1=t-13, guard checks t-8 before the
// stage barrier which orders it before the store) verified for both rings.
//
// r18 = r17 sentinel protocol, v2. r17 post-mortem: the +215us regression
// came from (a) L0 wave0's pre-store wait_ge(flag1,t-7) -- TIGHT every step
// (L0 leads L1 by exactly 8), serializing L0's store on L1's flag; with
// ring-16 the real requirement is t-13, and it is IMPLIED by the loaders'
// per-step spin guard (flag1 >= t-8) which the stage barrier orders before
// the store. (b) heavy spin rounds (re-load all 6 granules + flag each
// retry). Fixes:
//  1. NO producer-side waits at all: tail barrier -> data stores first ->
//     (L1: lazy clears) -> drain -> flag. Flag is off the data path.
//  2. LATCHING spins: granules/guard re-loaded only until first valid
//     (exec-masked); steady-state retry rounds shrink to the granules
//     still in flight. TIE lists all regs each round (fence discipline).
// Stale-occupant safety is STRUCTURAL (not probabilistic): consumer step-t
// loads issue only after its step-(t-7) spin observed flag1 >= t-15, which
// includes every peer's drained clear of the slot's old value h[t-16/17]
// (cursors pass by peer step ~t-16). Sentinel (0xFFFF = bf16 NaN,
// unreachable) covers the [clear, new-store] window.
// Everything else r17/r16: MALL primitives (sc0sc1 loads / agent-atomic
// stores), loader(w1-3)/storer(w0) split, in-register gate tail, h_lds8
// pack + wave0 coalesced 8B stores, L1 h0 LDS-prefetch dbuf, ring-16
// (slot(tau)=(tau+1)&15, slot0 = zeros = h[-1]), hot bounded polls.

#define NB    64
#define SEQL  256
#define INF   128
#define HID   512
#define OUTN  64
#define NWG   256
#define NT    256
#define NCNT  32
#define CADD  (NWG / NCNT)
#define PBOUND 8192

typedef __attribute__((ext_vector_type(8))) short  short8;
typedef __attribute__((ext_vector_type(4))) float  floatx4;
typedef unsigned short u16;
typedef unsigned long long u64;

#define TIE4(N, x0,x1,x2,x3)                                                \
  asm volatile("s_waitcnt vmcnt(" N ")" : "+v"(x0), "+v"(x1), "+v"(x2), "+v"(x3))
#define TIE2(N, x0,x1)                                                      \
  asm volatile("s_waitcnt vmcnt(" N ")" : "+v"(x0), "+v"(x1))

#define MFMA(ACC, A, B) \
  ACC = __builtin_amdgcn_mfma_f32_16x16x32_bf16((A), (B), ACC, 0, 0, 0)

__device__ __forceinline__ u16 f2bf(float f) {
  union { float f; unsigned u; } v; v.f = f;
  return (u16)((v.u + 0x7FFFu + ((v.u >> 16) & 1u)) >> 16);  // RNE
}
__device__ __forceinline__ float bf2f(u16 s) {
  union { unsigned u; float f; } v; v.u = ((unsigned)s) << 16;
  return v.f;
}
__device__ __forceinline__ float sigf(float v) {
  return __builtin_amdgcn_rcpf(1.f + __expf(-v));
}
__device__ __forceinline__ float tanh_fast(float v) {
  float cv = fminf(fmaxf(v, -15.f), 15.f);
  float e = __expf(2.f * cv);
  return (e - 1.f) * __builtin_amdgcn_rcpf(e + 1.f);
}

// ---- proven exchange primitives (r4/r5-validated on MI355X) ----
__device__ __forceinline__ short8 ldh(const u16* p) {
  short8 d;
  asm volatile("global_load_dwordx4 %0, %1, off sc0 sc1" : "=v"(d) : "v"(p));
  return d;
}
__device__ __forceinline__ void st8c(u16* p, u64 v) {
  __hip_atomic_store((u64*)p, v, __ATOMIC_RELAXED, __HIP_MEMORY_SCOPE_AGENT);
}
__device__ __forceinline__ unsigned ldf(const unsigned* p) {
  return __hip_atomic_load(p, __ATOMIC_RELAXED, __HIP_MEMORY_SCOPE_AGENT);
}

// granule validity: both 8B halves non-sentinel (producer stores are 8B
// atomics; 0xFFFF = bf16 NaN, unreachable by real h values)
__device__ __forceinline__ bool valid8(short8 v) {
  return ((u16)v[0] != 0xFFFFu) & ((u16)v[4] != 0xFFFFu);
}

// staging-granule LDS byte offset (XOR-swizzle byte ^= (b&7)<<4)
__device__ __forceinline__ int swz(int gi) {
  return (gi * 16) ^ (((gi >> 6) & 7) << 4);
}

// blocking flag wait (FC head only): lanes 0-15 poll f[0..15] >= thr.
__device__ __forceinline__ void wait_ge(const unsigned* f, int thr) {
  if (thr <= 0) return;
  const int lane = threadIdx.x & 63;
  const unsigned* p = (lane < 16) ? f + lane : nullptr;
  for (int i = 0; i < PBOUND; ++i) {
    int v = 0x7fffffff;
    if (p) v = (int)ldf(p);
    if (__all(v >= thr)) break;
    if (i > 2048) __builtin_amdgcn_s_sleep(2);
  }
  __builtin_amdgcn_sched_barrier(0);
  asm volatile("" ::: "memory");
}

// One-time MALL grid barrier (r5-proven shape), bounded poll.
__device__ __forceinline__ void grid_bar_once(unsigned* leaf, int w) {
  asm volatile("s_waitcnt vmcnt(0)" ::: "memory");
  __syncthreads();
  if (threadIdx.x == 0)
    __hip_atomic_fetch_add(&leaf[(w & (NCNT - 1)) * 32], 1u, __ATOMIC_RELAXED,
                           __HIP_MEMORY_SCOPE_AGENT);
  if (threadIdx.x < 64) {
    const int lane = threadIdx.x & 63;
    for (int i = 0; i < (1 << 16); ++i) {
      unsigned v = CADD;
      if (lane < NCNT) v = ldf(&leaf[lane * 32]);
      if (__all(v >= CADD)) break;
      __builtin_amdgcn_s_sleep(1);
    }
  }
  __syncthreads();
}

// 4x4 transpose across a lane quartet (lanes base..base+3, j = lane&3).
__device__ __forceinline__ floatx4 xpose4(floatx4 v, int jb0, int jb1) {
  floatx4 t;
#pragma unroll
  for (int r = 0; r < 4; ++r) t[r] = __shfl_xor(v[r], 1);
  floatx4 u;
  u[0] = jb0 ? t[1] : v[0];
  u[1] = jb0 ? v[1] : t[0];
  u[2] = jb0 ? t[3] : v[2];
  u[3] = jb0 ? v[3] : t[2];
  floatx4 s;
#pragma unroll
  for (int r = 0; r < 4; ++r) s[r] = __shfl_xor(u[r], 2);
  floatx4 w_;
  w_[0] = jb1 ? s[2] : u[0];
  w_[1] = jb1 ? s[3] : u[1];
  w_[2] = jb1 ? u[2] : s[0];
  w_[3] = jb1 ? u[3] : s[1];
  return w_;
}

// B-fragments (r9-shape, unchanged).
template <int KS, int KIN>
__device__ __forceinline__ void load_B(short8 (&Bf)[2][32],
                                       const float* __restrict__ Wih,
                                       const float* __restrict__ Whh,
                                       int li, int wv, int mrow, int quad) {
#pragma unroll
  for (int t2 = 0; t2 < 2; ++t2) {
    const int rowid = wv * 32 + t2 * 16 + mrow;
    const int r = (rowid & 3) * HID + 32 * li + (rowid >> 2);
    const float* wr = Wih + (size_t)r * KIN;
    const float* hr = Whh + (size_t)r * HID - KIN;   // hr[k]=Whh[r][k-KIN]
#pragma unroll
    for (int ks = 0; ks < KS; ++ks) {
      short8 v;
#pragma unroll
      for (int j = 0; j < 8; ++j) {
        const int k = 32 * ks + quad * 8 + j;
        v[j] = (short)f2bf(k < KIN ? wr[k] : hr[k]);
      }
      Bf[t2][ks] = v;
    }
  }
}

__global__ __launch_bounds__(NT, 1) void lstm_groups(
    const float* __restrict__ x,
    const float* __restrict__ Wih0, const float* __restrict__ Whh0,
    const float* __restrict__ bih0, const float* __restrict__ bhh0,
    const float* __restrict__ Wih1, const float* __restrict__ Whh1,
    const float* __restrict__ bih1, const float* __restrict__ bhh1,
    const float* __restrict__ Wfc,  const float* __restrict__ bfc,
    float* __restrict__ out,
    unsigned* __restrict__ leaf,
    unsigned* __restrict__ flag0, unsigned* __restrict__ flag1,
    u16* __restrict__ h0r, u16* __restrict__ h1r, u16* __restrict__ xg)
{
  const int w = blockIdx.x, tid = threadIdx.x;
  const int lane = tid & 63, wv = tid >> 6;
  const int quad = lane >> 4, mrow = lane & 15;
  const int g = w & 7, m = w >> 3;          // group, member (0..31)
  const bool isL1 = (m >= 16);
  const int  li   = isL1 ? m - 16 : m;      // layer-local WG index (0..15)

  __shared__ u64   h_lds8[8][8];
  __shared__ float red[16][17];
  // staging: [b(8)][k(512)] bf16 = 8KB per buffer, XOR-swizzle byte^=(b&7)<<4.
  // hA2: L0 h-stage (buf0 only) / L1 h0-prefetch dbuf.  hB: L1 h1-stage.
  __shared__ short8 hA2[2][512];
  __shared__ short8 hB[512];
  char* hAc = (char*)hA2;
  char* hBc = (char*)hB;

  // ---- xg fill: xg[g][t][b][k] bf16, 8 (g,t)-slices per WG, MALL stores ----
#pragma unroll
  for (int i = 0; i < 8; ++i) {
    const int s = w * 8 + i, gs = s >> 8, ts = s & 255;
    u16* dst = xg + (size_t)(gs * 256 + ts) * 1024;
    const int b = tid >> 5, k0 = (tid & 31) * 4;
    const float* src = x + ((size_t)(8 * gs + b) * SEQL + ts) * INF + k0;
    union { u16 h[4]; u64 u; } pk;
#pragma unroll
    for (int j = 0; j < 4; ++j) pk.h[j] = f2bf(src[j]);
    st8c(dst + b * 128 + k0, pk.u);
  }

  // ---- weights -> VGPR B-fragments; bias -> regs (folded into acc init) --
  short8 Bf[2][32];
  if (isL1) load_B<32, HID>(Bf, Wih1, Whh1, li, wv, mrow, quad);
  else      load_B<20, INF>(Bf, Wih0, Whh0, li, wv, mrow, quad);
  float bsA, bsB;
  {
    const int r0 = wv * 32 + mrow, r1 = r0 + 16;
    const int ra = (r0 & 3) * HID + 32 * li + (r0 >> 2);
    const int rb = (r1 & 3) * HID + 32 * li + (r1 >> 2);
    bsA = isL1 ? (bih1[ra] + bhh1[ra]) : (bih0[ra] + bhh0[ra]);
    bsB = isL1 ? (bih1[rb] + bhh1[rb]) : (bih0[rb] + bhh0[rb]);
  }

  grid_bar_once(leaf, w);   // xg visible everywhere; flags zero; rings init'd

  // flags: flag[g*64 + li] = t+1 (producer completed step t)
  unsigned* flag0g = flag0 + g * 64;
  unsigned* flag1g = flag1 + g * 64;
  // rings: 16 slots x 8KB; slot(tau) = (tau+1)&15; slot0 = zeros = h[-1]
  u16* h0g = h0r + (size_t)g * 65536;
  u16* h1g = h1r + (size_t)g * 65536;
  const u16* xgg = xg + (size_t)g * 256 * 1024;

  const int q4 = quad;
  const int m4 = mrow >> 2, jg = mrow & 3;
  const int jb0 = jg & 1, jb1 = (jg >> 1) & 1;
  float cstA = 0.f, cstB = 0.f;
  const int ab = mrow & 7;
  const int koff = quad * 8;

  const bool ldr = (wv != 0);        // loader waves 1-3; wave 0 = storer
  const int base = tid - 64;         // loader granule base (0..191)
  int c0 = -1, c1 = -1;              // L1 wave0 clear cursors (next s to clear)

  // L1 pre-stage: sentinel-poll h0[0] (slot 1) -> hA2 buf0. All 256 threads.
  if (isL1) {
    const u16* sp = h0g + 1 * 4096;
    short8 s0 = {}, s1 = {};
    bool v0 = false, v1 = false;
    for (int it = 0; it < PBOUND; ++it) {
      if (!v0) s0 = ldh(sp + tid * 8);
      if (!v1) s1 = ldh(sp + (tid + 256) * 8);
      TIE2("0", s0, s1);
      v0 = v0 || valid8(s0);
      v1 = v1 || valid8(s1);
      if (__all(v0 & v1)) break;
      if (it > 2048) __builtin_amdgcn_s_sleep(2);
    }
    __builtin_amdgcn_sched_barrier(0);
    *(short8*)(hAc + swz(tid)) = s0;
    *(short8*)(hAc + swz(tid + 256)) = s1;
    __syncthreads();
  }

  for (int t = 0; t < SEQL; ++t) {
    floatx4 a00 = {bsA, bsA, bsA, bsA}, a01 = {0,0,0,0};
    floatx4 a10 = {bsB, bsB, bsB, bsB}, a11 = {0,0,0,0};
    const int pb = (t & 1) * 8192;        // L1 prefetch: current buffer
    const int nb_ = ((t + 1) & 1) * 8192; // L1 prefetch: next buffer
    const int thr = t - 8;                // loader stale-guard (slack, free)

    if (!isL1) {
      // x-part: cached xg loads + 8 MFMAs (all waves, before any wait)
      const u16* xa = xgg + (size_t)t * 1024 + ab * 128 + koff;
      short8 x0 = *(const short8*)(xa +  0);
      short8 x1 = *(const short8*)(xa + 32);
      short8 x2 = *(const short8*)(xa + 64);
      short8 x3 = *(const short8*)(xa + 96);
      MFMA(a00,x0,Bf[0][0]);  MFMA(a10,x0,Bf[1][0]);
      MFMA(a01,x1,Bf[0][1]);  MFMA(a11,x1,Bf[1][1]);
      MFMA(a00,x2,Bf[0][2]);  MFMA(a10,x2,Bf[1][2]);
      MFMA(a01,x3,Bf[0][3]);  MFMA(a11,x3,Bf[1][3]);

      if (ldr) {
        // latching sentinel-spin: h0[t-1] (slot t&15) + flag1>=t-8 guard
        const u16* src = h0g + (t & 15) * 4096;
        const bool g2 = (base < 128);
        short8 s0 = {}, s1 = {}, s2 = {};
        bool v0 = false, v1 = false, v2 = !g2;
        bool gk = (thr <= 0) || (lane >= 16);
        int fl = 0;
        for (int it = 0; it < PBOUND; ++it) {
          if (!v0) s0 = ldh(src + base * 8);
          if (!v1) s1 = ldh(src + (base + 192) * 8);
          if (!v2) s2 = ldh(src + (base + 384) * 8);
          if (!gk) fl = (int)ldf(flag1g + lane);
          asm volatile("s_waitcnt vmcnt(0)"
                       : "+v"(s0), "+v"(s1), "+v"(s2) :: "memory");
          v0 = v0 || valid8(s0);
          v1 = v1 || valid8(s1);
          v2 = v2 || valid8(s2);
          gk = gk || (fl >= thr);
          if (__all(v0 & v1 & v2 & gk)) break;
          if (it > 2048) __builtin_amdgcn_s_sleep(2);
        }
        __builtin_amdgcn_sched_barrier(0);
        *(short8*)(hAc + swz(base)) = s0;
        *(short8*)(hAc + swz(base + 192)) = s1;
        if (g2) *(short8*)(hAc + swz(base + 384)) = s2;
      }
      __syncthreads();   // stage-publish barrier

#pragma unroll
      for (int n = 0; n < 16; ++n) {
        const short8 fv = *(const short8*)(
            hAc + ((ab * 1024 + n * 64 + quad * 16) ^ (ab << 4)));
        if ((n & 1) == 0) { MFMA(a00, fv, Bf[0][4 + n]); MFMA(a10, fv, Bf[1][4 + n]); }
        else              { MFMA(a01, fv, Bf[0][4 + n]); MFMA(a11, fv, Bf[1][4 + n]); }
      }
    } else {
      const bool pf = (t < 255);           // prefetch h0[t+1] exists
      if (ldr) {
        const u16* srcB = h1g + (t & 15) * 4096;        // h1[t-1]
        const u16* srcP = h0g + ((t + 2) & 15) * 4096;  // h0[t+1]
        const bool g2 = (base < 128);
        short8 b0 = {}, b1 = {}, b2 = {}, p0 = {}, p1 = {}, p2 = {};
        bool vb0 = false, vb1 = false, vb2 = !g2;
        bool vp0 = !pf, vp1 = !pf, vp2 = !(pf && g2);
        bool gk = (thr <= 0) || (lane >= 16);
        int fl = 0;
        // round 0: issue everything, fill the flight with the h0 MFMAs
        b0 = ldh(srcB + base * 8);
        b1 = ldh(srcB + (base + 192) * 8);
        if (g2) b2 = ldh(srcB + (base + 384) * 8);
        if (pf) {
          p0 = ldh(srcP + base * 8);
          p1 = ldh(srcP + (base + 192) * 8);
          if (g2) p2 = ldh(srcP + (base + 384) * 8);
        }
        if (!gk) fl = (int)ldf(flag1g + lane);
        __builtin_amdgcn_sched_barrier(0);
#pragma unroll
        for (int n = 0; n < 16; ++n) {
          const short8 fv = *(const short8*)(
              hAc + pb + ((ab * 1024 + n * 64 + quad * 16) ^ (ab << 4)));
          if ((n & 1) == 0) { MFMA(a00, fv, Bf[0][n]); MFMA(a10, fv, Bf[1][n]); }
          else              { MFMA(a01, fv, Bf[0][n]); MFMA(a11, fv, Bf[1][n]); }
        }
        for (int it = 0; it < PBOUND; ++it) {
          if (it) {   // latching re-issue: only granules still in flight
            if (!vb0) b0 = ldh(srcB + base * 8);
            if (!vb1) b1 = ldh(srcB + (base + 192) * 8);
            if (!vb2) b2 = ldh(srcB + (base + 384) * 8);
            if (!vp0) p0 = ldh(srcP + base * 8);
            if (!vp1) p1 = ldh(srcP + (base + 192) * 8);
            if (!vp2) p2 = ldh(srcP + (base + 384) * 8);
            if (!gk)  fl = (int)ldf(flag1g + lane);
          }
          asm volatile("s_waitcnt vmcnt(0)"
                       : "+v"(b0), "+v"(b1), "+v"(b2),
                         "+v"(p0), "+v"(p1), "+v"(p2) :: "memory");
          vb0 = vb0 || valid8(b0);
          vb1 = vb1 || valid8(b1);
          vb2 = vb2 || valid8(b2);
          vp0 = vp0 || valid8(p0);
          vp1 = vp1 || valid8(p1);
          vp2 = vp2 || valid8(p2);
          gk  = gk  || (fl >= thr);
          if (__all(vb0 & vb1 & vb2 & vp0 & vp1 & vp2 & gk)) break;
          if (it > 2048) __builtin_amdgcn_s_sleep(2);
        }
        __builtin_amdgcn_sched_barrier(0);
        *(short8*)(hBc + swz(base)) = b0;
        *(short8*)(hBc + swz(base + 192)) = b1;
        if (g2) *(short8*)(hBc + swz(base + 384)) = b2;
        if (pf) {
          *(short8*)(hAc + nb_ + swz(base)) = p0;
          *(short8*)(hAc + nb_ + swz(base + 192)) = p1;
          if (g2) *(short8*)(hAc + nb_ + swz(base + 384)) = p2;
        }
      } else {
        // wave0: its 16 h0-part MFMAs from prefetched LDS
#pragma unroll
        for (int n = 0; n < 16; ++n) {
          const short8 fv = *(const short8*)(
              hAc + pb + ((ab * 1024 + n * 64 + quad * 16) ^ (ab << 4)));
          if ((n & 1) == 0) { MFMA(a00, fv, Bf[0][n]); MFMA(a10, fv, Bf[1][n]); }
          else              { MFMA(a01, fv, Bf[0][n]); MFMA(a11, fv, Bf[1][n]); }
        }
      }
      __syncthreads();   // stage-publish barrier (hB + hA[nb_])

#pragma unroll
      for (int n = 0; n < 16; ++n) {
        const short8 fv = *(const short8*)(
            hBc + ((ab * 1024 + n * 64 + quad * 16) ^ (ab << 4)));
        if ((n & 1) == 0) { MFMA(a00, fv, Bf[0][16 + n]); MFMA(a10, fv, Bf[1][16 + n]); }
        else              { MFMA(a01, fv, Bf[0][16 + n]); MFMA(a11, fv, Bf[1][16 + n]); }
      }
    }

    // ---- in-register tail: transpose -> gates -> h_lds8 ----
    const floatx4 vA = a00 + a01, vB = a10 + a11;
    if (lane < 32) {
      const floatx4 gA = xpose4(vA, jb0, jb1);
      const floatx4 gB = xpose4(vB, jb0, jb1);
      const float cA = sigf(gA[1]) * cstA + sigf(gA[0]) * tanh_fast(gA[2]);
      const float cB = sigf(gB[1]) * cstB + sigf(gB[0]) * tanh_fast(gB[2]);
      cstA = cA; cstB = cB;
      u16* hl = (u16*)&h_lds8[q4 * 4 + jg][0];
      hl[wv * 8 + m4]     = f2bf(sigf(gA[3]) * tanh_fast(cA));
      hl[wv * 8 + m4 + 4] = f2bf(sigf(gB[3]) * tanh_fast(cB));
    }
    __syncthreads();   // tail-publish barrier

    if (wv == 0) {
      u16* ring = isL1 ? h1g : h0g;
      // DATA STORES FIRST, no producer-side wait: consumers' spins see the
      // data as it lands. WAR safety (clears landed) is implied by this
      // step's loader guard (flag1 >= t-8 observed before the stage
      // barrier; requirement is only t-13 with ring-16).
      {
        const int b = tid >> 3, u8 = tid & 7;
        const u64 v = h_lds8[b][u8];
        st8c(ring + ((t + 1) & 15) * 4096 + b * 512 + li * 32 + u8 * 4, v);
      }
      if (isL1) {
        // flag snapshot (one round) -> advance clear cursors
        unsigned vmin = 0x7fffffffu;
        if (lane < 16)       vmin = ldf(flag0g + lane);
        else if (lane < 32)  vmin = ldf(flag1g + lane - 16);
#pragma unroll
        for (int o = 1; o < 16; o <<= 1) {
          unsigned ov = (unsigned)__shfl_xor((int)vmin, o);
          vmin = vmin < ov ? vmin : ov;
        }
        const int m0 = __shfl((int)vmin, 0);
        const int m1 = __shfl((int)vmin, 16);
        int tgt0 = m0 - 2; if (m1 - 1 < tgt0) tgt0 = m1 - 1;
        if (t - 1 < tgt0) tgt0 = t - 1;
        while (c0 <= tgt0) {   // clear h0[c0] (slot (c0+1)&15), li-range
          st8c(h0g + ((c0 + 1) & 15) * 4096 + li * 256 + lane * 4,
               0xFFFFFFFFFFFFFFFFull);
          ++c0;
        }
        int tgt1 = m1 - 2; if (t - 1 < tgt1) tgt1 = t - 1;
        while (c1 <= tgt1) {   // clear h1[c1], li-range
          st8c(h1g + ((c1 + 1) & 15) * 4096 + li * 256 + lane * 4,
               0xFFFFFFFFFFFFFFFFull);
          ++c1;
        }
      }
      // drain (stores + clears) then publish flag (guards + FC only)
      asm volatile("s_waitcnt vmcnt(0)" ::: "memory");
      if (tid == 0)
        __hip_atomic_store((isL1 ? flag1g : flag0g) + li, (unsigned)(t + 1),
                           __ATOMIC_RELAXED, __HIP_MEMORY_SCOPE_AGENT);
    }
  }

  // ---- FC head: out[b][o] = h1_255[b] . Wfc[o] + bfc[o] ----
  // h1[255] lives in slot 0. Flag wait = completion + drain.
  wait_ge(flag1g, 256);
  {
    const int bloc = m >> 2, oq = m & 3;    // 32 members = 8 b x 4 o-blocks
    const int ol = tid >> 4, ksub = tid & 15;
    const u16* hp = h1g + 0 * 4096 + bloc * 512 + ksub * 32;
    short8 v0 = ldh(hp),      v1 = ldh(hp + 8);
    short8 v2 = ldh(hp + 16), v3 = ldh(hp + 24);
    TIE4("0", v0, v1, v2, v3);
    const float* wr = Wfc + (size_t)(oq * 16 + ol) * HID + ksub * 32;
    float s = 0.f;
#pragma unroll
    for (int j = 0; j < 8; ++j) {
      s += bf2f((u16)v0[j]) * wr[j];
      s += bf2f((u16)v1[j]) * wr[8 + j];
      s += bf2f((u16)v2[j]) * wr[16 + j];
      s += bf2f((u16)v3[j]) * wr[24 + j];
    }
    red[ol][ksub] = s;
    __syncthreads();
    if (tid < 16) {
      float sum = 0.f;
#pragma unroll
      for (int j = 0; j < 16; ++j) sum += red[tid][j];
      out[(size_t)(8 * g + bloc) * OUTN + oq * 16 + tid] = sum + bfc[oq * 16 + tid];
    }
  }
}

// Workspace layout (bytes):
//   [256, 4352)          one-time barrier leaves (32 x 128B)
//   [8192, 10240)        flag0[8][64] u32 (per-WG monotonic, 16 used)
//   [16384, 18432)       flag1[8][64] u32
//   [32768, 1081344)     h0 rings: 8 groups x 16 slots x 8 b x 512 k bf16
//   [1081344, 2129920)   h1 rings (same shape)
//   [2129920, 6324224)   xg: 8 groups x 256 t x 8 b x 128 k bf16
// init: [0,32768)=0; rings=0xFF (sentinel); slot0 of each group/ring = 0
// (valid h[-1] zeros); xg fully written by kernel.

extern "C" void kernel_launch(void* const* d_in, const int* in_sizes, int n_in,
                              void* d_out, int out_size, void* d_ws, size_t ws_size,
                              hipStream_t stream) {
  (void)in_sizes; (void)n_in; (void)out_size; (void)ws_size;

  char* ws = (char*)d_ws;
  unsigned* leaf  = (unsigned*)(ws + 256);
  unsigned* flag0 = (unsigned*)(ws + 8192);
  unsigned* flag1 = (unsigned*)(ws + 16384);
  u16* h0r = (u16*)(ws + 32768);
  u16* h1r = (u16*)(ws + 1081344);
  u16* xg  = (u16*)(ws + 2129920);

  hipMemsetAsync(d_ws, 0, 32768, stream);                 // leaf + flags
  hipMemsetAsync(ws + 32768, 0xFF, 2097152, stream);      // rings -> sentinel
  for (int gg = 0; gg < 8; ++gg) {                        // slot0 -> zeros
    hipMemsetAsync(ws + 32768   + gg * 131072, 0, 8192, stream);
    hipMemsetAsync(ws + 1081344 + gg * 131072, 0, 8192, stream);
  }

  const float* x    = (const float*)d_in[0];
  const float* Wih0 = (const float*)d_in[1];
  const float* Whh0 = (const float*)d_in[2];
  const float* bih0 = (const float*)d_in[3];
  const float* bhh0 = (const float*)d_in[4];
  const float* Wih1 = (const float*)d_in[5];
  const float* Whh1 = (const float*)d_in[6];
  const float* bih1 = (const float*)d_in[7];
  const float* bhh1 = (const float*)d_in[8];
  const float* Wfc  = (const float*)d_in[9];
  const float* bfc  = (const float*)d_in[10];
  float* out = (float*)d_out;

  void* args[] = {
    (void*)&x,
    (void*)&Wih0, (void*)&Whh0, (void*)&bih0, (void*)&bhh0,
    (void*)&Wih1, (void*)&Whh1, (void*)&bih1, (void*)&bhh1,
    (void*)&Wfc,  (void*)&bfc,
    (void*)&out,
    (void*)&leaf, (void*)&flag0, (void*)&flag1,
    (void*)&h0r, (void*)&h1r, (void*)&xg
  };
  hipError_t err = hipLaunchCooperativeKernel((const void*)lstm_groups,
                                              dim3(NWG), dim3(NT), args, 0, stream);
  if (err != hipSuccess) {
    // 256 blocks @ 1 block/CU on 256 CUs are co-resident structurally.
    hipLaunchKernelGGL(lstm_groups, dim3(NWG), dim3(NT), 0, stream,
                       x, Wih0, Whh0, bih0, bhh0, Wih1, Whh1, bih1, bhh1,
                       Wfc, bfc, out, leaf, flag0, flag1, h0r, h1r, xg);
  }
}